// Round 8
// baseline (1256.466 us; speedup 1.0000x reference)
//
#include <hip/hip_runtime.h>
#include <hip/hip_bf16.h>

#define DIM 64

typedef _Float16 f16;
typedef _Float16 half8 __attribute__((ext_vector_type(8)));
typedef _Float16 half4 __attribute__((ext_vector_type(4)));

// ---------------- dtype detection ----------------
// flags: [0]=u_f32 [1]=i_f32 [2]=w_f32 [3]=ui_i64 [4]=ii_i64
__global__ void k_detect(const unsigned short* __restrict__ ue,
                         const unsigned short* __restrict__ ie,
                         const unsigned short* __restrict__ we,
                         const unsigned int* __restrict__ uidx,
                         const unsigned int* __restrict__ iidx,
                         int* __restrict__ flags) {
  if (threadIdx.x != 0 || blockIdx.x != 0) return;
  auto isf32 = [](const unsigned short* p) {
    for (int i = 0; i < 256; ++i)
      if (((p[i] >> 7) & 0xFF) >= 142) return 1;  // f32 mantissa garbage as bf16
    return 0;
  };
  auto is64 = [](const unsigned int* p) {
    for (int i = 0; i < 64; ++i)
      if (p[2 * i + 1] != 0u) return 0;
    return 1;
  };
  flags[0] = isf32(ue);
  flags[1] = isf32(ie);
  flags[2] = isf32(we);
  flags[3] = is64(uidx);
  flags[4] = is64(iidx);
}

__device__ __forceinline__ int load_idx(const int* p, int e, int f64) {
  return f64 ? (int)((const long long*)p)[e] : p[e];
}

// ---------------- degree, XCD-chunked ----------------
// Round-7 rocprof: flat atomic degree = 238 us, WRITE_SIZE 187 MB for a
// 600 KB array. 6M device-scope atomics over 150K counters make each deg
// line migrate between per-XCD L2s (dirty writeback per move) -> ~300x
// write amplification + cross-XCD serialization. Fix (same pattern as the
// round-3 scatter fix): group blockIdx&7 owns an N/8 node range; each group
// streams all edges, counts only its own nodes. Its 75 KB chunk stays hot
// in ONE XCD's L2 (atomics local, line evicted once). 8x index re-stream is
// LLC-served (~192 MB @ ~5 TB/s).
__global__ __launch_bounds__(256) void k_degree(
    const int* __restrict__ ui, const int* __restrict__ ii,
    const int* __restrict__ flags,
    int* __restrict__ deg, int E, int NU, int N) {
  const int f3 = flags[3], f4 = flags[4];
  const int grp = blockIdx.x & 7;   // presumed XCD id
  const int gb = blockIdx.x >> 3;   // block index within group
  const int ngb = gridDim.x >> 3;   // blocks per group
  const int chunk = (N + 7) >> 3;
  const int rlo = grp * chunk;
  const int rhi = min(N, rlo + chunk);
  for (int e = gb * 256 + (int)threadIdx.x; e < E; e += ngb * 256) {
    int u = load_idx(ui, e, f3);
    int it = NU + load_idx(ii, e, f4);
    if (u >= rlo && u < rhi) atomicAdd(&deg[u], 1);
    if (it >= rlo && it < rhi) atomicAdd(&deg[it], 1);
  }
}

__global__ void k_dinv(const int* __restrict__ deg, float* __restrict__ dinv, int N) {
  int i = blockIdx.x * blockDim.x + threadIdx.x;
  if (i < N) dinv[i] = rsqrtf((float)deg[i] + 1e-10f);
}

// ---------------- prescale: xs[r][d] = fp16(dinv[r] * x[r][d]) ----------------
__global__ void k_prescale(const void* __restrict__ xA, const void* __restrict__ xB,
                           int split, const float* __restrict__ dinv,
                           const int* __restrict__ flags,
                           f16* __restrict__ xs, int N) {
  int i = blockIdx.x * blockDim.x + threadIdx.x;  // quad index
  int total = N * (DIM / 4);
  if (i >= total) return;
  int r = i >> 4;      // 16 quads per row
  int q = i & 15;
  const float dv = dinv[r];
  const int f = (r < split) ? flags[0] : flags[1];
  const void* base = (r < split) ? xA : xB;
  size_t o = (size_t)(r < split ? r : r - split) * DIM + (q << 2);
  float v0, v1, v2, v3;
  if (f) {
    float4 x4 = *(const float4*)((const float*)base + o);
    v0 = x4.x; v1 = x4.y; v2 = x4.z; v3 = x4.w;
  } else {
    ushort4 x4 = *(const ushort4*)((const unsigned short*)base + o);
    v0 = __uint_as_float((unsigned)x4.x << 16);
    v1 = __uint_as_float((unsigned)x4.y << 16);
    v2 = __uint_as_float((unsigned)x4.z << 16);
    v3 = __uint_as_float((unsigned)x4.w << 16);
  }
  half4 h;
  h[0] = (f16)(v0 * dv); h[1] = (f16)(v1 * dv);
  h[2] = (f16)(v2 * dv); h[3] = (f16)(v3 * dv);
  *(half4*)(xs + (size_t)r * DIM + (q << 2)) = h;
}

// ---------------- exclusive scan over PADDED degrees (3-phase) ----------------
__global__ void k_scan1(const int* __restrict__ deg, int* __restrict__ bsum, int N) {
  __shared__ int s[256];
  int i = blockIdx.x * 256 + threadIdx.x;
  s[threadIdx.x] = (i < N) ? ((deg[i] + 3) & ~3) : 0;
  __syncthreads();
  for (int off = 128; off > 0; off >>= 1) {
    if (threadIdx.x < off) s[threadIdx.x] += s[threadIdx.x + off];
    __syncthreads();
  }
  if (threadIdx.x == 0) bsum[blockIdx.x] = s[0];
}

__global__ void k_scan2(int* __restrict__ bsum, int nb) {
  __shared__ int s[1024];
  int t = threadIdx.x;
  int v = (t < nb) ? bsum[t] : 0;
  s[t] = v;
  __syncthreads();
  for (int off = 1; off < 1024; off <<= 1) {
    int tmp = (t >= off) ? s[t - off] : 0;
    __syncthreads();
    s[t] += tmp;
    __syncthreads();
  }
  if (t < nb) bsum[t] = s[t] - v;  // exclusive
}

__global__ void k_scan3(const int* __restrict__ deg, const int* __restrict__ bsum,
                        int* __restrict__ row_ptr, int N) {
  __shared__ int s[256];
  int t = threadIdx.x;
  int i = blockIdx.x * 256 + t;
  int v = (i < N) ? ((deg[i] + 3) & ~3) : 0;
  s[t] = v;
  __syncthreads();
  for (int off = 1; off < 256; off <<= 1) {
    int tmp = (t >= off) ? s[t - off] : 0;
    __syncthreads();
    s[t] += tmp;
    __syncthreads();
  }
  if (i < N) row_ptr[i] = bsum[blockIdx.x] + s[t] - v;
}

// ---------------- generic exclusive scan (no padding), for the bin matrix ----
__global__ void g_scan1(const int* __restrict__ in, int* __restrict__ bsum, int n) {
  __shared__ int s[256];
  int i = blockIdx.x * 256 + threadIdx.x;
  s[threadIdx.x] = (i < n) ? in[i] : 0;
  __syncthreads();
  for (int off = 128; off > 0; off >>= 1) {
    if (threadIdx.x < off) s[threadIdx.x] += s[threadIdx.x + off];
    __syncthreads();
  }
  if (threadIdx.x == 0) bsum[blockIdx.x] = s[0];
}

__global__ void g_scan3(const int* __restrict__ in, const int* __restrict__ bsum,
                        int* __restrict__ out, int n) {
  __shared__ int s[256];
  int t = threadIdx.x;
  int i = blockIdx.x * 256 + t;
  int v = (i < n) ? in[i] : 0;
  s[t] = v;
  __syncthreads();
  for (int off = 1; off < 256; off <<= 1) {
    int tmp = (t >= off) ? s[t - off] : 0;
    __syncthreads();
    s[t] += tmp;
    __syncthreads();
  }
  if (i < n) out[i] = bsum[blockIdx.x] + s[t] - v;
}

// ============= CSR build, two-level binning — ZERO global atomics in binning =============
// History: direct scatter = 14x ECC-RMW write amplification (rounds 2-5);
// round-6 global-atomic frontiers = 1994 us serialization. Round-7 (this
// structure) fixed both: LDS histograms + private per-(bucket,block)
// segments + XCD-affine windowed scatter. Measured: whole chain below the
// 238 us degree kernel.

#define NBKT 128   // bucket slots (real buckets NB <= 127 by SHIFT choice)
#define NBLK 1024  // binning blocks; pass A and pass C MUST both use this grid

__global__ __launch_bounds__(256) void k_bcount(
    const int* __restrict__ ui, const int* __restrict__ ii,
    const int* __restrict__ flags, const int* __restrict__ row_ptr,
    int* __restrict__ bcnt, int E, int NU, int SHIFT_) {
  __shared__ int hist[NBKT];
  if (threadIdx.x < NBKT) hist[threadIdx.x] = 0;
  __syncthreads();
  const int f3 = flags[3], f4 = flags[4];
  for (int e = blockIdx.x * 256 + (int)threadIdx.x; e < E; e += gridDim.x * 256) {
    int u = load_idx(ui, e, f3);
    int it = NU + load_idx(ii, e, f4);
    atomicAdd(&hist[row_ptr[u] >> SHIFT_], 1);   // LDS atomic
    atomicAdd(&hist[row_ptr[it] >> SHIFT_], 1);  // LDS atomic
  }
  __syncthreads();
  if (threadIdx.x < NBKT)
    bcnt[threadIdx.x * NBLK + blockIdx.x] = hist[threadIdx.x];
}

__global__ __launch_bounds__(256) void k_bin2(
    const int* __restrict__ ui, const int* __restrict__ ii,
    const int* __restrict__ flags, const int* __restrict__ row_ptr,
    const int* __restrict__ bbase, unsigned long long* __restrict__ pairs,
    int E, int NU, int SHIFT_) {
  __shared__ int cur[NBKT];
  if (threadIdx.x < NBKT)
    cur[threadIdx.x] = bbase[threadIdx.x * NBLK + blockIdx.x];
  __syncthreads();
  const int f3 = flags[3], f4 = flags[4];
  for (int e = blockIdx.x * 256 + (int)threadIdx.x; e < E; e += gridDim.x * 256) {
    int u = load_idx(ui, e, f3);
    int it = NU + load_idx(ii, e, f4);
    int p1 = atomicAdd(&cur[row_ptr[u] >> SHIFT_], 1);   // LDS atomic
    int p2 = atomicAdd(&cur[row_ptr[it] >> SHIFT_], 1);  // LDS atomic
    // pair: lo = dst, hi = src
    pairs[p1] = ((unsigned long long)(unsigned)it << 32) | (unsigned)u;
    pairs[p2] = ((unsigned long long)(unsigned)u << 32) | (unsigned)it;
  }
}

// bucket b's pairs are contiguous: [bbase[b*NBLK], bbase[(b+1)*NBLK]).
// block -> (bucket, slice) with b&7 == blockIdx&7 so each bucket's 256 KB
// cols window stays on one XCD's L2.
__global__ __launch_bounds__(256) void k_scatter2(
    const unsigned long long* __restrict__ pairs, const int* __restrict__ bbase,
    const int* __restrict__ row_ptr, int* __restrict__ cnt,
    int* __restrict__ cols, int nseg2, int twoE) {
  const int bper = NBKT >> 3;           // buckets per XCD lane
  const int x = blockIdx.x & 7;
  const int y = blockIdx.x >> 3;
  const int b = (y % bper) * 8 + x;     // bucket (b&7 == blockIdx&7 -> XCD affinity)
  const int slice = y / bper;
  const int nslice = (gridDim.x >> 3) / bper;
  const int rstart = bbase[b * NBLK];
  const int endIdx = (b + 1) * NBLK;
  const int rend = (endIdx < nseg2) ? bbase[endIdx] : twoE;
  for (int i = rstart + slice * 256 + (int)threadIdx.x; i < rend; i += nslice * 256) {
    unsigned long long p = pairs[i];
    int dst = (int)(unsigned)(p & 0xffffffffULL);
    int src = (int)(unsigned)(p >> 32);
    cols[row_ptr[dst] + atomicAdd(&cnt[dst], 1)] = src;
  }
}

// ---------------- legacy single-pass scatter (ws_size fallback; round-4) ------
__global__ __launch_bounds__(256) void k_scatter_legacy(
    const int* __restrict__ ui, const int* __restrict__ ii,
    const int* __restrict__ flags, const int* __restrict__ row_ptr,
    int* __restrict__ cnt, int* __restrict__ cols, int E, int NU, int N) {
  const int f3 = flags[3], f4 = flags[4];
  const int grp = blockIdx.x & 7;
  const int gb = blockIdx.x >> 3;
  const int ngb = gridDim.x >> 3;
  const int chunk = (N + 7) >> 3;
  const int rlo = grp * chunk;
  const int rhi = min(N, rlo + chunk);
  for (int e = gb * 256 + (int)threadIdx.x; e < E; e += ngb * 256) {
    int u = load_idx(ui, e, f3);
    int it = NU + load_idx(ii, e, f4);
    if (u >= rlo && u < rhi)
      cols[row_ptr[u] + atomicAdd(&cnt[u], 1)] = it;
    if (it >= rlo && it < rhi)
      cols[row_ptr[it] + atomicAdd(&cnt[it], 1)] = u;
  }
}

// ---------------- pure gather: agg[r][:] = sum_{c in N(r)} gsrc[c][:] ----------------
// (round-4 structure; plain loads — nt hints regressed in round 5.)
// Wave layout: lane = 8*g + t; group g does 4 edges/iter via one int4 cols
// load; lane t covers dims 8t..8t+7 as one 16B load. dinv_r applied later.
__global__ __launch_bounds__(256) void k_gather(
    const int* __restrict__ row_ptr, const int* __restrict__ deg,
    const int* __restrict__ cols, const f16* __restrict__ gsrc,
    float* __restrict__ agg, int N) {
  const int wave = threadIdx.x >> 6;
  const int lane = threadIdx.x & 63;
  const int g = lane >> 3;  // edge-slot group 0..7
  const int t = lane & 7;   // dim chunk: dims 8t..8t+7
  const int stride = gridDim.x * 4;
  const f16* pb = gsrc + (t << 3);

  for (int r = blockIdx.x * 4 + wave; r < N; r += stride) {
    const int start = row_ptr[r];  // multiple of 4 (padded CSR)
    const int end = start + deg[r];

    float sv[8] = {0.f, 0.f, 0.f, 0.f, 0.f, 0.f, 0.f, 0.f};

    int e = start;
    if (e + 32 <= end) {
      int4 c4 = *(const int4*)(cols + e + (g << 2));  // 16B aligned
      for (; e + 32 <= end;) {
        // prefetch next iteration's cols (stays inside padded allocation;
        // garbage indices are never dereferenced)
        int4 c4n = *(const int4*)(cols + e + 32 + (g << 2));
        half8 v0 = *(const half8*)(pb + ((size_t)c4.x << 6));
        half8 v1 = *(const half8*)(pb + ((size_t)c4.y << 6));
        half8 v2 = *(const half8*)(pb + ((size_t)c4.z << 6));
        half8 v3 = *(const half8*)(pb + ((size_t)c4.w << 6));
#pragma unroll
        for (int k = 0; k < 8; ++k)
          sv[k] += ((float)v0[k] + (float)v1[k]) + ((float)v2[k] + (float)v3[k]);
        e += 32;
        c4 = c4n;
      }
    }
    int rem = end - e;
    if (rem > 0) {
      int4 c4 = *(const int4*)(cols + e + (g << 2));
      int k0 = g << 2;
#pragma unroll
      for (int j = 0; j < 4; ++j) {
        int cj = (j == 0) ? c4.x : (j == 1) ? c4.y : (j == 2) ? c4.z : c4.w;
        if (k0 + j < rem) {
          half8 v = *(const half8*)(pb + ((size_t)cj << 6));
#pragma unroll
          for (int k = 0; k < 8; ++k) sv[k] += (float)v[k];
        }
      }
    }

    // butterfly over the 8 edge groups -> every lane holds the full sums
#pragma unroll
    for (int k = 0; k < 8; ++k) {
      float s = sv[k];
      s += __shfl_xor(s, 8);
      s += __shfl_xor(s, 16);
      s += __shfl_xor(s, 32);
      sv[k] = s;
    }

    // lane (g,t) writes dim t*8+g with value sv[g]  (static-index select chain)
    float v = sv[0];
#pragma unroll
    for (int j = 1; j < 8; ++j) v = (g == j) ? sv[j] : v;
    agg[(size_t)r * DIM + (t << 3) + g] = v;
  }
}

// ---------------- streaming Linear + ReLU (+ final combine) ----------------
template <int MODE>
__global__ __launch_bounds__(256) void k_linear(
    const float* __restrict__ agg, const int* __restrict__ deg,
    const void* __restrict__ Wbase, int layer, const int* __restrict__ flags,
    const void* __restrict__ xA, const void* __restrict__ xB, int split,
    const f16* __restrict__ h1s, const f16* __restrict__ h2s,
    f16* __restrict__ houts, float* __restrict__ fout, int N) {
  const int fw = flags[2];
  __shared__ float Wt[64 * 64];  // Wt[k*64 + d] = W[l][d][k]
  for (int i = threadIdx.x; i < 64 * 64; i += 256) {
    float wv = fw ? ((const float*)Wbase)[layer * 4096 + i]
                  : __bfloat162float(((const __hip_bfloat16*)Wbase)[layer * 4096 + i]);
    int d = i >> 6, k = i & 63;
    Wt[(k << 6) + d] = wv;
  }
  __syncthreads();

  const int wave = threadIdx.x >> 6;
  const int lane = threadIdx.x & 63;  // = output dim d

  float w[64];  // W[d][k] for this lane's d (static indices only)
#pragma unroll
  for (int k = 0; k < 64; ++k) w[k] = Wt[(k << 6) + lane];

  const int fu = flags[0], fi = flags[1];
  const int stride = gridDim.x * 4;

  for (int r = blockIdx.x * 4 + wave; r < N; r += stride) {
    float a = agg[(size_t)r * DIM + lane];
    float lin = 0.f;
#pragma unroll
    for (int k = 0; k < 64; ++k) lin += __shfl(a, k) * w[k];

    const int dr = deg[r];
    const float dinv_r = rsqrtf((float)dr + 1e-10f);
    float hn = lin * dinv_r;
    hn = hn > 0.f ? hn : 0.f;

    size_t o = (size_t)r * DIM + lane;
    if constexpr (MODE == 2) {
      float xr;
      if (r < split) {
        size_t ox = (size_t)r * DIM + lane;
        xr = fu ? ((const float*)xA)[ox]
                : __bfloat162float(((const __hip_bfloat16*)xA)[ox]);
      } else {
        size_t ox = (size_t)(r - split) * DIM + lane;
        xr = fi ? ((const float*)xB)[ox]
                : __bfloat162float(((const __hip_bfloat16*)xB)[ox]);
      }
      float sr = sqrtf((float)dr + 1e-10f);  // un-scale stored h1s/h2s
      float h1v = (float)h1s[o] * sr;
      float h2v = (float)h2s[o] * sr;
      fout[o] = (xr + h1v + h2v + hn) * 0.25f;  // FLOAT32 output
    } else {
      houts[o] = (f16)(hn * dinv_r);
    }
  }
}

extern "C" void kernel_launch(void* const* d_in, const int* in_sizes, int n_in,
                              void* d_out, int out_size, void* d_ws, size_t ws_size,
                              hipStream_t stream) {
  const void* user_e = d_in[0];
  const void* item_e = d_in[1];
  const void* W = d_in[2];
  const int* ui = (const int*)d_in[3];
  const int* ii = (const int*)d_in[4];

  const int NU = in_sizes[0] / DIM;
  const int NI = in_sizes[1] / DIM;
  const int N = NU + NI;
  const int E = in_sizes[3];
  float* out = (float*)d_out;  // OUTPUT IS FLOAT32

  // bucket geometry: CE = cols-entry capacity; bucket window = 2^SHIFT entries
  const long long CE = 2LL * E + 4LL * N + 64;
  int SHIFT = 16;
  while (((CE + (1LL << SHIFT) - 1) >> SHIFT) > (NBKT - 1)) SHIFT++;
  const int NSEG2 = NBKT * NBLK;  // 131072 count-matrix entries
  const int twoE = 2 * E;

  // Workspace (~140 MB for N=150k, E=3M)
  auto align = [](size_t x) { return (x + 255) & ~(size_t)255; };
  char* w = (char*)d_ws;
  size_t off = 0;
  int* deg = (int*)(w + off);      off += align((size_t)N * 4);
  int* cnt = (int*)(w + off);      off += align((size_t)N * 4);
  int* bsum = (int*)(w + off);     off += align((size_t)4096 * 4);
  int* flags = (int*)(w + off);    off += align(256);
  size_t meta_zero_bytes = off;
  int* row_ptr = (int*)(w + off);  off += align((size_t)N * 4);
  float* dinv = (float*)(w + off); off += align((size_t)N * 4);
  int* cols = (int*)(w + off);     off += align((size_t)CE * 4);
  f16* xs = (f16*)(w + off);       off += align((size_t)N * DIM * 2);
  f16* h1s = (f16*)(w + off);      off += align((size_t)N * DIM * 2);
  f16* h2s = (f16*)(w + off);      off += align((size_t)N * DIM * 2);
  int* bcnt = (int*)(w + off);     off += align((size_t)NSEG2 * 4);
  int* bbase = (int*)(w + off);    off += align((size_t)NSEG2 * 4);
  // pairs (CSR build) and agg (layers) overlay: lifetimes don't intersect
  size_t off_union = off;
  float* agg = (float*)(w + off_union);
  unsigned long long* pairs = (unsigned long long*)(w + off_union);
  size_t agg_bytes = (size_t)N * DIM * 4;
  size_t pairs_bytes = (size_t)twoE * 8;
  size_t need_new = off_union + align(pairs_bytes > agg_bytes ? pairs_bytes : agg_bytes);
  const bool use2pass = (ws_size == 0) || (ws_size >= need_new);

  hipMemsetAsync(d_ws, 0, meta_zero_bytes, stream);

  k_detect<<<1, 64, 0, stream>>>((const unsigned short*)user_e,
                                 (const unsigned short*)item_e,
                                 (const unsigned short*)W,
                                 (const unsigned int*)ui,
                                 (const unsigned int*)ii, flags);

  const int TPB = 256;
  k_degree<<<2048, TPB, 0, stream>>>(ui, ii, flags, deg, E, NU, N);
  k_dinv<<<(N + TPB - 1) / TPB, TPB, 0, stream>>>(deg, dinv, N);
  k_prescale<<<(N * (DIM / 4) + TPB - 1) / TPB, TPB, 0, stream>>>(
      user_e, item_e, NU, dinv, flags, xs, N);

  int nb = (N + 255) / 256;  // 586 for N=150000, must be <= 1024
  k_scan1<<<nb, 256, 0, stream>>>(deg, bsum, N);
  k_scan2<<<1, 1024, 0, stream>>>(bsum, nb);
  k_scan3<<<nb, 256, 0, stream>>>(deg, bsum, row_ptr, N);

  if (use2pass) {
    k_bcount<<<NBLK, 256, 0, stream>>>(ui, ii, flags, row_ptr, bcnt, E, NU, SHIFT);
    int nb2 = NSEG2 / 256;  // 512 <= 1024
    g_scan1<<<nb2, 256, 0, stream>>>(bcnt, bsum, NSEG2);
    k_scan2<<<1, 1024, 0, stream>>>(bsum, nb2);
    g_scan3<<<nb2, 256, 0, stream>>>(bcnt, bsum, bbase, NSEG2);
    k_bin2<<<NBLK, 256, 0, stream>>>(ui, ii, flags, row_ptr, bbase, pairs, E, NU,
                                     SHIFT);
    k_scatter2<<<NBKT * 16, 256, 0, stream>>>(pairs, bbase, row_ptr, cnt, cols,
                                              NSEG2, twoE);
  } else {
    k_scatter_legacy<<<2048, 256, 0, stream>>>(ui, ii, flags, row_ptr, cnt,
                                               cols, E, NU, N);
  }

  const int GGRID = 4096;  // gather: fine-grained for load balance + full residency
  const int LGRID = 2048;

  k_gather<<<GGRID, 256, 0, stream>>>(row_ptr, deg, cols, xs, agg, N);
  k_linear<0><<<LGRID, 256, 0, stream>>>(agg, deg, W, 0, flags, user_e, item_e, NU,
                                         nullptr, nullptr, h1s, nullptr, N);
  k_gather<<<GGRID, 256, 0, stream>>>(row_ptr, deg, cols, h1s, agg, N);
  k_linear<1><<<LGRID, 256, 0, stream>>>(agg, deg, W, 1, flags, user_e, item_e, NU,
                                         nullptr, nullptr, h2s, nullptr, N);
  k_gather<<<GGRID, 256, 0, stream>>>(row_ptr, deg, cols, h2s, agg, N);
  k_linear<2><<<LGRID, 256, 0, stream>>>(agg, deg, W, 2, flags, user_e, item_e, NU,
                                         h1s, h2s, nullptr, out, N);
}

// Round 9
// 931.299 us; speedup vs baseline: 1.3492x; 1.3492x over previous
//
#include <hip/hip_runtime.h>
#include <hip/hip_bf16.h>

#define DIM 64

typedef _Float16 f16;
typedef _Float16 half8 __attribute__((ext_vector_type(8)));
typedef _Float16 half4 __attribute__((ext_vector_type(4)));

// ---------------- dtype detection ----------------
// flags: [0]=u_f32 [1]=i_f32 [2]=w_f32 [3]=ui_i64 [4]=ii_i64
__global__ void k_detect(const unsigned short* __restrict__ ue,
                         const unsigned short* __restrict__ ie,
                         const unsigned short* __restrict__ we,
                         const unsigned int* __restrict__ uidx,
                         const unsigned int* __restrict__ iidx,
                         int* __restrict__ flags) {
  if (threadIdx.x != 0 || blockIdx.x != 0) return;
  auto isf32 = [](const unsigned short* p) {
    for (int i = 0; i < 256; ++i)
      if (((p[i] >> 7) & 0xFF) >= 142) return 1;  // f32 mantissa garbage as bf16
    return 0;
  };
  auto is64 = [](const unsigned int* p) {
    for (int i = 0; i < 64; ++i)
      if (p[2 * i + 1] != 0u) return 0;
    return 1;
  };
  flags[0] = isf32(ue);
  flags[1] = isf32(ie);
  flags[2] = isf32(we);
  flags[3] = is64(uidx);
  flags[4] = is64(iidx);
}

__device__ __forceinline__ int load_idx(const int* p, int e, int f64) {
  return f64 ? (int)((const long long*)p)[e] : p[e];
}

// ---------------- legacy degree (fallback only) ----------------
// MEASURED (rounds 7+8): 6M device-scope atomicAdds cost 187 MB of HBM-class
// writes (~32 B/atomic) and ~240 us REGARDLESS of XCD chunking -> atomics
// execute memory-side on gfx950; locality tricks cannot help. The main path
// below computes degree with LDS counters instead.
__global__ __launch_bounds__(256) void k_degree_legacy(
    const int* __restrict__ ui, const int* __restrict__ ii,
    const int* __restrict__ flags,
    int* __restrict__ deg, int E, int NU, int N) {
  const int f3 = flags[3], f4 = flags[4];
  for (int e = blockIdx.x * 256 + (int)threadIdx.x; e < E; e += gridDim.x * 256) {
    atomicAdd(&deg[load_idx(ui, e, f3)], 1);
    atomicAdd(&deg[NU + load_idx(ii, e, f4)], 1);
  }
}

__global__ void k_dinv(const int* __restrict__ deg, float* __restrict__ dinv, int N) {
  int i = blockIdx.x * blockDim.x + threadIdx.x;
  if (i < N) dinv[i] = rsqrtf((float)deg[i] + 1e-10f);
}

// ---------------- prescale: xs[r][d] = fp16(dinv[r] * x[r][d]) ----------------
__global__ void k_prescale(const void* __restrict__ xA, const void* __restrict__ xB,
                           int split, const float* __restrict__ dinv,
                           const int* __restrict__ flags,
                           f16* __restrict__ xs, int N) {
  int i = blockIdx.x * blockDim.x + threadIdx.x;  // quad index
  int total = N * (DIM / 4);
  if (i >= total) return;
  int r = i >> 4;      // 16 quads per row
  int q = i & 15;
  const float dv = dinv[r];
  const int f = (r < split) ? flags[0] : flags[1];
  const void* base = (r < split) ? xA : xB;
  size_t o = (size_t)(r < split ? r : r - split) * DIM + (q << 2);
  float v0, v1, v2, v3;
  if (f) {
    float4 x4 = *(const float4*)((const float*)base + o);
    v0 = x4.x; v1 = x4.y; v2 = x4.z; v3 = x4.w;
  } else {
    ushort4 x4 = *(const ushort4*)((const unsigned short*)base + o);
    v0 = __uint_as_float((unsigned)x4.x << 16);
    v1 = __uint_as_float((unsigned)x4.y << 16);
    v2 = __uint_as_float((unsigned)x4.z << 16);
    v3 = __uint_as_float((unsigned)x4.w << 16);
  }
  half4 h;
  h[0] = (f16)(v0 * dv); h[1] = (f16)(v1 * dv);
  h[2] = (f16)(v2 * dv); h[3] = (f16)(v3 * dv);
  *(half4*)(xs + (size_t)r * DIM + (q << 2)) = h;
}

// ---------------- exclusive scan over PADDED degrees (3-phase) ----------------
__global__ void k_scan1(const int* __restrict__ deg, int* __restrict__ bsum, int N) {
  __shared__ int s[256];
  int i = blockIdx.x * 256 + threadIdx.x;
  s[threadIdx.x] = (i < N) ? ((deg[i] + 3) & ~3) : 0;
  __syncthreads();
  for (int off = 128; off > 0; off >>= 1) {
    if (threadIdx.x < off) s[threadIdx.x] += s[threadIdx.x + off];
    __syncthreads();
  }
  if (threadIdx.x == 0) bsum[blockIdx.x] = s[0];
}

__global__ void k_scan2(int* __restrict__ bsum, int nb) {
  __shared__ int s[1024];
  int t = threadIdx.x;
  int v = (t < nb) ? bsum[t] : 0;
  s[t] = v;
  __syncthreads();
  for (int off = 1; off < 1024; off <<= 1) {
    int tmp = (t >= off) ? s[t - off] : 0;
    __syncthreads();
    s[t] += tmp;
    __syncthreads();
  }
  if (t < nb) bsum[t] = s[t] - v;  // exclusive
}

__global__ void k_scan3(const int* __restrict__ deg, const int* __restrict__ bsum,
                        int* __restrict__ row_ptr, int N) {
  __shared__ int s[256];
  int t = threadIdx.x;
  int i = blockIdx.x * 256 + t;
  int v = (i < N) ? ((deg[i] + 3) & ~3) : 0;
  s[t] = v;
  __syncthreads();
  for (int off = 1; off < 256; off <<= 1) {
    int tmp = (t >= off) ? s[t - off] : 0;
    __syncthreads();
    s[t] += tmp;
    __syncthreads();
  }
  if (i < N) row_ptr[i] = bsum[blockIdx.x] + s[t] - v;
}

// ---------------- generic exclusive scan (no padding), for the bin matrix ----
__global__ void g_scan1(const int* __restrict__ in, int* __restrict__ bsum, int n) {
  __shared__ int s[256];
  int i = blockIdx.x * 256 + threadIdx.x;
  s[threadIdx.x] = (i < n) ? in[i] : 0;
  __syncthreads();
  for (int off = 128; off > 0; off >>= 1) {
    if (threadIdx.x < off) s[threadIdx.x] += s[threadIdx.x + off];
    __syncthreads();
  }
  if (threadIdx.x == 0) bsum[blockIdx.x] = s[0];
}

__global__ void g_scan3(const int* __restrict__ in, const int* __restrict__ bsum,
                        int* __restrict__ out, int n) {
  __shared__ int s[256];
  int t = threadIdx.x;
  int i = blockIdx.x * 256 + t;
  int v = (i < n) ? in[i] : 0;
  s[t] = v;
  __syncthreads();
  for (int off = 1; off < 256; off <<= 1) {
    int tmp = (t >= off) ? s[t - off] : 0;
    __syncthreads();
    s[t] += tmp;
    __syncthreads();
  }
  if (i < n) out[i] = bsum[blockIdx.x] + s[t] - v;
}

// ============= CSR build, NODE-SPACE binning — zero global atomics anywhere ====
// Lesson history:
//   rounds 2-5: direct scatter = 14x ECC-RMW write amplification.
//   round 6:    global-atomic frontiers = 1994 us serialization.
//   rounds 7-8: remaining 6M-atomic kernels (degree, scatter cnt) each cost
//               ~32 B HBM write + serialization PER ATOMIC, locality-immune.
// This version keys buckets on dst >> NODE_SHIFT (node id — available BEFORE
// degree). Each bucket = contiguous <=1024-node range, so per-bucket kernels
// hold degree counters / scatter cursors entirely in LDS:
//   k_bcount_n: per-block LDS histogram -> private count row (plain stores).
//   g_scan:     262144-entry exclusive scan -> per-(bucket,block) bases.
//   k_bin2_n:   append pairs via LDS cursors into private segments.
//   k_builddeg: per bucket: LDS-count degrees from pairs, coalesced deg store.
//   k_scatter_n:per bucket: slot = row_ptr[dst] + LDS-cursor; cols write lands
//               in the bucket's ~100-160 KB L2-resident window.

#define NBKT 512   // node-range buckets (one block each in builddeg/scatter)
#define NBLK 512   // binning blocks; bcount and bin2 MUST share this grid
#define RNG_MAX 1024

__global__ __launch_bounds__(256) void k_bcount_n(
    const int* __restrict__ ui, const int* __restrict__ ii,
    const int* __restrict__ flags, int* __restrict__ bcnt,
    int E, int NU, int NODE_SHIFT) {
  __shared__ int hist[NBKT];
  for (int j = threadIdx.x; j < NBKT; j += 256) hist[j] = 0;
  __syncthreads();
  const int f3 = flags[3], f4 = flags[4];
  for (int e = blockIdx.x * 256 + (int)threadIdx.x; e < E; e += gridDim.x * 256) {
    int u = load_idx(ui, e, f3);
    int it = NU + load_idx(ii, e, f4);
    atomicAdd(&hist[u >> NODE_SHIFT], 1);   // LDS atomic
    atomicAdd(&hist[it >> NODE_SHIFT], 1);  // LDS atomic
  }
  __syncthreads();
  for (int j = threadIdx.x; j < NBKT; j += 256)
    bcnt[j * NBLK + blockIdx.x] = hist[j];
}

__global__ __launch_bounds__(256) void k_bin2_n(
    const int* __restrict__ ui, const int* __restrict__ ii,
    const int* __restrict__ flags, const int* __restrict__ bbase,
    unsigned long long* __restrict__ pairs, int E, int NU, int NODE_SHIFT) {
  __shared__ int cur[NBKT];
  for (int j = threadIdx.x; j < NBKT; j += 256)
    cur[j] = bbase[j * NBLK + blockIdx.x];
  __syncthreads();
  const int f3 = flags[3], f4 = flags[4];
  for (int e = blockIdx.x * 256 + (int)threadIdx.x; e < E; e += gridDim.x * 256) {
    int u = load_idx(ui, e, f3);
    int it = NU + load_idx(ii, e, f4);
    int p1 = atomicAdd(&cur[u >> NODE_SHIFT], 1);   // LDS atomic
    int p2 = atomicAdd(&cur[it >> NODE_SHIFT], 1);  // LDS atomic
    // pair: lo = dst, hi = src
    pairs[p1] = ((unsigned long long)(unsigned)it << 32) | (unsigned)u;
    pairs[p2] = ((unsigned long long)(unsigned)u << 32) | (unsigned)it;
  }
}

// one block per bucket: count degrees of the bucket's node range in LDS,
// then write deg[] with coalesced plain stores (zero-degree nodes get 0).
__global__ __launch_bounds__(256) void k_builddeg(
    const unsigned long long* __restrict__ pairs, const int* __restrict__ bbase,
    int* __restrict__ deg, int N, int NODE_SHIFT, int twoE) {
  __shared__ int ldeg[RNG_MAX];
  const int rng = 1 << NODE_SHIFT;
  for (int j = threadIdx.x; j < rng; j += 256) ldeg[j] = 0;
  __syncthreads();
  const int b = blockIdx.x;
  const int pstart = bbase[b * NBLK];
  const int pend = ((b + 1) * NBLK < NBKT * NBLK) ? bbase[(b + 1) * NBLK] : twoE;
  const int mask = rng - 1;
  for (int i = pstart + (int)threadIdx.x; i < pend; i += 256) {
    int dst = (int)(unsigned)(pairs[i] & 0xffffffffULL);
    atomicAdd(&ldeg[dst & mask], 1);  // LDS atomic
  }
  __syncthreads();
  const int node0 = b << NODE_SHIFT;
  for (int j = threadIdx.x; j < rng; j += 256) {
    int n = node0 + j;
    if (n < N) deg[n] = ldeg[j];
  }
}

// one block per bucket: scatter the bucket's pairs into cols using LDS
// cursors; writes land in the bucket's contiguous cols window (L2-resident).
__global__ __launch_bounds__(256) void k_scatter_n(
    const unsigned long long* __restrict__ pairs, const int* __restrict__ bbase,
    const int* __restrict__ row_ptr, int* __restrict__ cols,
    int NODE_SHIFT, int twoE) {
  __shared__ int lcnt[RNG_MAX];
  const int rng = 1 << NODE_SHIFT;
  for (int j = threadIdx.x; j < rng; j += 256) lcnt[j] = 0;
  __syncthreads();
  const int b = blockIdx.x;
  const int pstart = bbase[b * NBLK];
  const int pend = ((b + 1) * NBLK < NBKT * NBLK) ? bbase[(b + 1) * NBLK] : twoE;
  const int mask = rng - 1;
  for (int i = pstart + (int)threadIdx.x; i < pend; i += 256) {
    unsigned long long p = pairs[i];
    int dst = (int)(unsigned)(p & 0xffffffffULL);
    int src = (int)(unsigned)(p >> 32);
    int slot = row_ptr[dst] + atomicAdd(&lcnt[dst & mask], 1);  // LDS atomic
    cols[slot] = src;
  }
}

// ---------------- legacy single-pass scatter (ws_size fallback; round-4) ------
__global__ __launch_bounds__(256) void k_scatter_legacy(
    const int* __restrict__ ui, const int* __restrict__ ii,
    const int* __restrict__ flags, const int* __restrict__ row_ptr,
    int* __restrict__ cnt, int* __restrict__ cols, int E, int NU, int N) {
  const int f3 = flags[3], f4 = flags[4];
  const int grp = blockIdx.x & 7;
  const int gb = blockIdx.x >> 3;
  const int ngb = gridDim.x >> 3;
  const int chunk = (N + 7) >> 3;
  const int rlo = grp * chunk;
  const int rhi = min(N, rlo + chunk);
  for (int e = gb * 256 + (int)threadIdx.x; e < E; e += ngb * 256) {
    int u = load_idx(ui, e, f3);
    int it = NU + load_idx(ii, e, f4);
    if (u >= rlo && u < rhi)
      cols[row_ptr[u] + atomicAdd(&cnt[u], 1)] = it;
    if (it >= rlo && it < rhi)
      cols[row_ptr[it] + atomicAdd(&cnt[it], 1)] = u;
  }
}

// ---------------- pure gather: agg[r][:] = sum_{c in N(r)} gsrc[c][:] ----------------
// (round-4 structure; plain loads — nt hints regressed in round 5.)
// Wave layout: lane = 8*g + t; group g does 4 edges/iter via one int4 cols
// load; lane t covers dims 8t..8t+7 as one 16B load. dinv_r applied later.
__global__ __launch_bounds__(256) void k_gather(
    const int* __restrict__ row_ptr, const int* __restrict__ deg,
    const int* __restrict__ cols, const f16* __restrict__ gsrc,
    float* __restrict__ agg, int N) {
  const int wave = threadIdx.x >> 6;
  const int lane = threadIdx.x & 63;
  const int g = lane >> 3;  // edge-slot group 0..7
  const int t = lane & 7;   // dim chunk: dims 8t..8t+7
  const int stride = gridDim.x * 4;
  const f16* pb = gsrc + (t << 3);

  for (int r = blockIdx.x * 4 + wave; r < N; r += stride) {
    const int start = row_ptr[r];  // multiple of 4 (padded CSR)
    const int end = start + deg[r];

    float sv[8] = {0.f, 0.f, 0.f, 0.f, 0.f, 0.f, 0.f, 0.f};

    int e = start;
    if (e + 32 <= end) {
      int4 c4 = *(const int4*)(cols + e + (g << 2));  // 16B aligned
      for (; e + 32 <= end;) {
        // prefetch next iteration's cols (stays inside padded allocation;
        // garbage indices are never dereferenced)
        int4 c4n = *(const int4*)(cols + e + 32 + (g << 2));
        half8 v0 = *(const half8*)(pb + ((size_t)c4.x << 6));
        half8 v1 = *(const half8*)(pb + ((size_t)c4.y << 6));
        half8 v2 = *(const half8*)(pb + ((size_t)c4.z << 6));
        half8 v3 = *(const half8*)(pb + ((size_t)c4.w << 6));
#pragma unroll
        for (int k = 0; k < 8; ++k)
          sv[k] += ((float)v0[k] + (float)v1[k]) + ((float)v2[k] + (float)v3[k]);
        e += 32;
        c4 = c4n;
      }
    }
    int rem = end - e;
    if (rem > 0) {
      int4 c4 = *(const int4*)(cols + e + (g << 2));
      int k0 = g << 2;
#pragma unroll
      for (int j = 0; j < 4; ++j) {
        int cj = (j == 0) ? c4.x : (j == 1) ? c4.y : (j == 2) ? c4.z : c4.w;
        if (k0 + j < rem) {
          half8 v = *(const half8*)(pb + ((size_t)cj << 6));
#pragma unroll
          for (int k = 0; k < 8; ++k) sv[k] += (float)v[k];
        }
      }
    }

    // butterfly over the 8 edge groups -> every lane holds the full sums
#pragma unroll
    for (int k = 0; k < 8; ++k) {
      float s = sv[k];
      s += __shfl_xor(s, 8);
      s += __shfl_xor(s, 16);
      s += __shfl_xor(s, 32);
      sv[k] = s;
    }

    // lane (g,t) writes dim t*8+g with value sv[g]  (static-index select chain)
    float v = sv[0];
#pragma unroll
    for (int j = 1; j < 8; ++j) v = (g == j) ? sv[j] : v;
    agg[(size_t)r * DIM + (t << 3) + g] = v;
  }
}

// ---------------- streaming Linear + ReLU (+ final combine) ----------------
template <int MODE>
__global__ __launch_bounds__(256) void k_linear(
    const float* __restrict__ agg, const int* __restrict__ deg,
    const void* __restrict__ Wbase, int layer, const int* __restrict__ flags,
    const void* __restrict__ xA, const void* __restrict__ xB, int split,
    const f16* __restrict__ h1s, const f16* __restrict__ h2s,
    f16* __restrict__ houts, float* __restrict__ fout, int N) {
  const int fw = flags[2];
  __shared__ float Wt[64 * 64];  // Wt[k*64 + d] = W[l][d][k]
  for (int i = threadIdx.x; i < 64 * 64; i += 256) {
    float wv = fw ? ((const float*)Wbase)[layer * 4096 + i]
                  : __bfloat162float(((const __hip_bfloat16*)Wbase)[layer * 4096 + i]);
    int d = i >> 6, k = i & 63;
    Wt[(k << 6) + d] = wv;
  }
  __syncthreads();

  const int wave = threadIdx.x >> 6;
  const int lane = threadIdx.x & 63;  // = output dim d

  float w[64];  // W[d][k] for this lane's d (static indices only)
#pragma unroll
  for (int k = 0; k < 64; ++k) w[k] = Wt[(k << 6) + lane];

  const int fu = flags[0], fi = flags[1];
  const int stride = gridDim.x * 4;

  for (int r = blockIdx.x * 4 + wave; r < N; r += stride) {
    float a = agg[(size_t)r * DIM + lane];
    float lin = 0.f;
#pragma unroll
    for (int k = 0; k < 64; ++k) lin += __shfl(a, k) * w[k];

    const int dr = deg[r];
    const float dinv_r = rsqrtf((float)dr + 1e-10f);
    float hn = lin * dinv_r;
    hn = hn > 0.f ? hn : 0.f;

    size_t o = (size_t)r * DIM + lane;
    if constexpr (MODE == 2) {
      float xr;
      if (r < split) {
        size_t ox = (size_t)r * DIM + lane;
        xr = fu ? ((const float*)xA)[ox]
                : __bfloat162float(((const __hip_bfloat16*)xA)[ox]);
      } else {
        size_t ox = (size_t)(r - split) * DIM + lane;
        xr = fi ? ((const float*)xB)[ox]
                : __bfloat162float(((const __hip_bfloat16*)xB)[ox]);
      }
      float sr = sqrtf((float)dr + 1e-10f);  // un-scale stored h1s/h2s
      float h1v = (float)h1s[o] * sr;
      float h2v = (float)h2s[o] * sr;
      fout[o] = (xr + h1v + h2v + hn) * 0.25f;  // FLOAT32 output
    } else {
      houts[o] = (f16)(hn * dinv_r);
    }
  }
}

extern "C" void kernel_launch(void* const* d_in, const int* in_sizes, int n_in,
                              void* d_out, int out_size, void* d_ws, size_t ws_size,
                              hipStream_t stream) {
  const void* user_e = d_in[0];
  const void* item_e = d_in[1];
  const void* W = d_in[2];
  const int* ui = (const int*)d_in[3];
  const int* ii = (const int*)d_in[4];

  const int NU = in_sizes[0] / DIM;
  const int NI = in_sizes[1] / DIM;
  const int N = NU + NI;
  const int E = in_sizes[3];
  float* out = (float*)d_out;  // OUTPUT IS FLOAT32

  // node-space bucket geometry: rng = 2^NODE_SHIFT nodes per bucket
  int NODE_SHIFT = 0;
  while (((N + (1 << NODE_SHIFT) - 1) >> NODE_SHIFT) > NBKT) NODE_SHIFT++;
  const bool node_ok = ((1 << NODE_SHIFT) <= RNG_MAX);  // N <= NBKT*RNG_MAX
  const long long CE = 2LL * E + 4LL * N + 64;  // padded CSR capacity
  const int NSEG2 = NBKT * NBLK;  // 262144 count-matrix entries
  const int twoE = 2 * E;

  // Workspace (~140 MB for N=150k, E=3M)
  auto align = [](size_t x) { return (x + 255) & ~(size_t)255; };
  char* w = (char*)d_ws;
  size_t off = 0;
  int* deg = (int*)(w + off);      off += align((size_t)N * 4);
  int* cnt = (int*)(w + off);      off += align((size_t)N * 4);
  int* bsum = (int*)(w + off);     off += align((size_t)4096 * 4);
  int* flags = (int*)(w + off);    off += align(256);
  size_t meta_zero_bytes = off;
  int* row_ptr = (int*)(w + off);  off += align((size_t)N * 4);
  float* dinv = (float*)(w + off); off += align((size_t)N * 4);
  int* cols = (int*)(w + off);     off += align((size_t)CE * 4);
  f16* xs = (f16*)(w + off);       off += align((size_t)N * DIM * 2);
  f16* h1s = (f16*)(w + off);      off += align((size_t)N * DIM * 2);
  f16* h2s = (f16*)(w + off);      off += align((size_t)N * DIM * 2);
  int* bcnt = (int*)(w + off);     off += align((size_t)NSEG2 * 4);
  int* bbase = (int*)(w + off);    off += align((size_t)NSEG2 * 4);
  // pairs (CSR build) and agg (layers) overlay: lifetimes don't intersect
  size_t off_union = off;
  float* agg = (float*)(w + off_union);
  unsigned long long* pairs = (unsigned long long*)(w + off_union);
  size_t agg_bytes = (size_t)N * DIM * 4;
  size_t pairs_bytes = (size_t)twoE * 8;
  size_t need_new = off_union + align(pairs_bytes > agg_bytes ? pairs_bytes : agg_bytes);
  const bool use2pass = node_ok && ((ws_size == 0) || (ws_size >= need_new));

  hipMemsetAsync(d_ws, 0, meta_zero_bytes, stream);

  k_detect<<<1, 64, 0, stream>>>((const unsigned short*)user_e,
                                 (const unsigned short*)item_e,
                                 (const unsigned short*)W,
                                 (const unsigned int*)ui,
                                 (const unsigned int*)ii, flags);

  const int TPB = 256;
  int nb = (N + 255) / 256;  // 586 for N=150000, must be <= 1024

  if (use2pass) {
    // ---- node-space binning: no global atomics anywhere ----
    k_bcount_n<<<NBLK, 256, 0, stream>>>(ui, ii, flags, bcnt, E, NU, NODE_SHIFT);
    int nb2 = NSEG2 / 256;  // 1024
    g_scan1<<<nb2, 256, 0, stream>>>(bcnt, bsum, NSEG2);
    k_scan2<<<1, 1024, 0, stream>>>(bsum, nb2);
    g_scan3<<<nb2, 256, 0, stream>>>(bcnt, bsum, bbase, NSEG2);
    k_bin2_n<<<NBLK, 256, 0, stream>>>(ui, ii, flags, bbase, pairs, E, NU,
                                       NODE_SHIFT);
    k_builddeg<<<NBKT, 256, 0, stream>>>(pairs, bbase, deg, N, NODE_SHIFT, twoE);
    k_dinv<<<(N + TPB - 1) / TPB, TPB, 0, stream>>>(deg, dinv, N);
    k_prescale<<<(N * (DIM / 4) + TPB - 1) / TPB, TPB, 0, stream>>>(
        user_e, item_e, NU, dinv, flags, xs, N);
    k_scan1<<<nb, 256, 0, stream>>>(deg, bsum, N);
    k_scan2<<<1, 1024, 0, stream>>>(bsum, nb);
    k_scan3<<<nb, 256, 0, stream>>>(deg, bsum, row_ptr, N);
    k_scatter_n<<<NBKT, 256, 0, stream>>>(pairs, bbase, row_ptr, cols,
                                          NODE_SHIFT, twoE);
  } else {
    // ---- fallback: global-atomic degree + legacy chunked scatter ----
    k_degree_legacy<<<2048, TPB, 0, stream>>>(ui, ii, flags, deg, E, NU, N);
    k_dinv<<<(N + TPB - 1) / TPB, TPB, 0, stream>>>(deg, dinv, N);
    k_prescale<<<(N * (DIM / 4) + TPB - 1) / TPB, TPB, 0, stream>>>(
        user_e, item_e, NU, dinv, flags, xs, N);
    k_scan1<<<nb, 256, 0, stream>>>(deg, bsum, N);
    k_scan2<<<1, 1024, 0, stream>>>(bsum, nb);
    k_scan3<<<nb, 256, 0, stream>>>(deg, bsum, row_ptr, N);
    k_scatter_legacy<<<2048, 256, 0, stream>>>(ui, ii, flags, row_ptr, cnt,
                                               cols, E, NU, N);
  }

  const int GGRID = 4096;  // gather: fine-grained for load balance + full residency
  const int LGRID = 2048;

  k_gather<<<GGRID, 256, 0, stream>>>(row_ptr, deg, cols, xs, agg, N);
  k_linear<0><<<LGRID, 256, 0, stream>>>(agg, deg, W, 0, flags, user_e, item_e, NU,
                                         nullptr, nullptr, h1s, nullptr, N);
  k_gather<<<GGRID, 256, 0, stream>>>(row_ptr, deg, cols, h1s, agg, N);
  k_linear<1><<<LGRID, 256, 0, stream>>>(agg, deg, W, 1, flags, user_e, item_e, NU,
                                         nullptr, nullptr, h2s, nullptr, N);
  k_gather<<<GGRID, 256, 0, stream>>>(row_ptr, deg, cols, h2s, agg, N);
  k_linear<2><<<LGRID, 256, 0, stream>>>(agg, deg, W, 2, flags, user_e, item_e, NU,
                                         h1s, h2s, nullptr, out, N);
}

// Round 10
// 738.534 us; speedup vs baseline: 1.7013x; 1.2610x over previous
//
#include <hip/hip_runtime.h>
#include <hip/hip_bf16.h>

#define DIM 64

typedef _Float16 f16;
typedef _Float16 half8 __attribute__((ext_vector_type(8)));
typedef _Float16 half4 __attribute__((ext_vector_type(4)));

// ---------------- dtype detection ----------------
// flags: [0]=u_f32 [1]=i_f32 [2]=w_f32 [3]=ui_i64 [4]=ii_i64
__global__ void k_detect(const unsigned short* __restrict__ ue,
                         const unsigned short* __restrict__ ie,
                         const unsigned short* __restrict__ we,
                         const unsigned int* __restrict__ uidx,
                         const unsigned int* __restrict__ iidx,
                         int* __restrict__ flags) {
  if (threadIdx.x != 0 || blockIdx.x != 0) return;
  auto isf32 = [](const unsigned short* p) {
    for (int i = 0; i < 256; ++i)
      if (((p[i] >> 7) & 0xFF) >= 142) return 1;  // f32 mantissa garbage as bf16
    return 0;
  };
  auto is64 = [](const unsigned int* p) {
    for (int i = 0; i < 64; ++i)
      if (p[2 * i + 1] != 0u) return 0;
    return 1;
  };
  flags[0] = isf32(ue);
  flags[1] = isf32(ie);
  flags[2] = isf32(we);
  flags[3] = is64(uidx);
  flags[4] = is64(iidx);
}

__device__ __forceinline__ int load_idx(const int* p, int e, int f64) {
  return f64 ? (int)((const long long*)p)[e] : p[e];
}

// ---------------- legacy degree (fallback only) ----------------
// MEASURED (rounds 7+8): 6M device-scope atomicAdds cost 187 MB of HBM-class
// writes (~32 B/atomic) and ~240 us REGARDLESS of XCD chunking -> atomics
// execute memory-side on gfx950; locality tricks cannot help. The main path
// below computes degree with LDS counters instead.
__global__ __launch_bounds__(256) void k_degree_legacy(
    const int* __restrict__ ui, const int* __restrict__ ii,
    const int* __restrict__ flags,
    int* __restrict__ deg, int E, int NU, int N) {
  const int f3 = flags[3], f4 = flags[4];
  for (int e = blockIdx.x * 256 + (int)threadIdx.x; e < E; e += gridDim.x * 256) {
    atomicAdd(&deg[load_idx(ui, e, f3)], 1);
    atomicAdd(&deg[NU + load_idx(ii, e, f4)], 1);
  }
}

__global__ void k_dinv(const int* __restrict__ deg, float* __restrict__ dinv, int N) {
  int i = blockIdx.x * blockDim.x + threadIdx.x;
  if (i < N) dinv[i] = rsqrtf((float)deg[i] + 1e-10f);
}

// ---------------- prescale: xs[r][d] = fp16(dinv[r] * x[r][d]) ----------------
__global__ void k_prescale(const void* __restrict__ xA, const void* __restrict__ xB,
                           int split, const float* __restrict__ dinv,
                           const int* __restrict__ flags,
                           f16* __restrict__ xs, int N) {
  int i = blockIdx.x * blockDim.x + threadIdx.x;  // quad index
  int total = N * (DIM / 4);
  if (i >= total) return;
  int r = i >> 4;      // 16 quads per row
  int q = i & 15;
  const float dv = dinv[r];
  const int f = (r < split) ? flags[0] : flags[1];
  const void* base = (r < split) ? xA : xB;
  size_t o = (size_t)(r < split ? r : r - split) * DIM + (q << 2);
  float v0, v1, v2, v3;
  if (f) {
    float4 x4 = *(const float4*)((const float*)base + o);
    v0 = x4.x; v1 = x4.y; v2 = x4.z; v3 = x4.w;
  } else {
    ushort4 x4 = *(const ushort4*)((const unsigned short*)base + o);
    v0 = __uint_as_float((unsigned)x4.x << 16);
    v1 = __uint_as_float((unsigned)x4.y << 16);
    v2 = __uint_as_float((unsigned)x4.z << 16);
    v3 = __uint_as_float((unsigned)x4.w << 16);
  }
  half4 h;
  h[0] = (f16)(v0 * dv); h[1] = (f16)(v1 * dv);
  h[2] = (f16)(v2 * dv); h[3] = (f16)(v3 * dv);
  *(half4*)(xs + (size_t)r * DIM + (q << 2)) = h;
}

// ---------------- exclusive scan over PADDED degrees (3-phase) ----------------
__global__ void k_scan1(const int* __restrict__ deg, int* __restrict__ bsum, int N) {
  __shared__ int s[256];
  int i = blockIdx.x * 256 + threadIdx.x;
  s[threadIdx.x] = (i < N) ? ((deg[i] + 3) & ~3) : 0;
  __syncthreads();
  for (int off = 128; off > 0; off >>= 1) {
    if (threadIdx.x < off) s[threadIdx.x] += s[threadIdx.x + off];
    __syncthreads();
  }
  if (threadIdx.x == 0) bsum[blockIdx.x] = s[0];
}

__global__ void k_scan2(int* __restrict__ bsum, int nb) {
  __shared__ int s[1024];
  int t = threadIdx.x;
  int v = (t < nb) ? bsum[t] : 0;
  s[t] = v;
  __syncthreads();
  for (int off = 1; off < 1024; off <<= 1) {
    int tmp = (t >= off) ? s[t - off] : 0;
    __syncthreads();
    s[t] += tmp;
    __syncthreads();
  }
  if (t < nb) bsum[t] = s[t] - v;  // exclusive
}

__global__ void k_scan3(const int* __restrict__ deg, const int* __restrict__ bsum,
                        int* __restrict__ row_ptr, int N) {
  __shared__ int s[256];
  int t = threadIdx.x;
  int i = blockIdx.x * 256 + t;
  int v = (i < N) ? ((deg[i] + 3) & ~3) : 0;
  s[t] = v;
  __syncthreads();
  for (int off = 1; off < 256; off <<= 1) {
    int tmp = (t >= off) ? s[t - off] : 0;
    __syncthreads();
    s[t] += tmp;
    __syncthreads();
  }
  if (i < N) row_ptr[i] = bsum[blockIdx.x] + s[t] - v;
}

// ---------------- generic exclusive scan (no padding), for the bin matrix ----
__global__ void g_scan1(const int* __restrict__ in, int* __restrict__ bsum, int n) {
  __shared__ int s[256];
  int i = blockIdx.x * 256 + threadIdx.x;
  s[threadIdx.x] = (i < n) ? in[i] : 0;
  __syncthreads();
  for (int off = 128; off > 0; off >>= 1) {
    if (threadIdx.x < off) s[threadIdx.x] += s[threadIdx.x + off];
    __syncthreads();
  }
  if (threadIdx.x == 0) bsum[blockIdx.x] = s[0];
}

__global__ void g_scan3(const int* __restrict__ in, const int* __restrict__ bsum,
                        int* __restrict__ out, int n) {
  __shared__ int s[256];
  int t = threadIdx.x;
  int i = blockIdx.x * 256 + t;
  int v = (i < n) ? in[i] : 0;
  s[t] = v;
  __syncthreads();
  for (int off = 1; off < 256; off <<= 1) {
    int tmp = (t >= off) ? s[t - off] : 0;
    __syncthreads();
    s[t] += tmp;
    __syncthreads();
  }
  if (i < n) out[i] = bsum[blockIdx.x] + s[t] - v;
}

// ============= CSR build, NODE-SPACE binning — zero global atomics anywhere ====
// Lesson history:
//   rounds 2-5: direct scatter = 14x ECC-RMW write amplification.
//   round 6:    global-atomic frontiers = 1994 us serialization.
//   rounds 7-8: remaining 6M-atomic kernels (degree, scatter cnt) each cost
//               ~32 B HBM write + serialization PER ATOMIC, locality-immune.
// Buckets keyed on dst >> NODE_SHIFT (node id — available BEFORE degree).
// Each bucket = contiguous <=1024-node range, so per-bucket kernels hold
// degree counters / scatter cursors entirely in LDS. (round 9: 1256->931 us)

#define NBKT 512   // node-range buckets (one block each in builddeg/scatter)
#define NBLK 512   // binning blocks; bcount and bin2 MUST share this grid
#define RNG_MAX 1024

__global__ __launch_bounds__(256) void k_bcount_n(
    const int* __restrict__ ui, const int* __restrict__ ii,
    const int* __restrict__ flags, int* __restrict__ bcnt,
    int E, int NU, int NODE_SHIFT) {
  __shared__ int hist[NBKT];
  for (int j = threadIdx.x; j < NBKT; j += 256) hist[j] = 0;
  __syncthreads();
  const int f3 = flags[3], f4 = flags[4];
  for (int e = blockIdx.x * 256 + (int)threadIdx.x; e < E; e += gridDim.x * 256) {
    int u = load_idx(ui, e, f3);
    int it = NU + load_idx(ii, e, f4);
    atomicAdd(&hist[u >> NODE_SHIFT], 1);   // LDS atomic
    atomicAdd(&hist[it >> NODE_SHIFT], 1);  // LDS atomic
  }
  __syncthreads();
  for (int j = threadIdx.x; j < NBKT; j += 256)
    bcnt[j * NBLK + blockIdx.x] = hist[j];
}

__global__ __launch_bounds__(256) void k_bin2_n(
    const int* __restrict__ ui, const int* __restrict__ ii,
    const int* __restrict__ flags, const int* __restrict__ bbase,
    unsigned long long* __restrict__ pairs, int E, int NU, int NODE_SHIFT) {
  __shared__ int cur[NBKT];
  for (int j = threadIdx.x; j < NBKT; j += 256)
    cur[j] = bbase[j * NBLK + blockIdx.x];
  __syncthreads();
  const int f3 = flags[3], f4 = flags[4];
  for (int e = blockIdx.x * 256 + (int)threadIdx.x; e < E; e += gridDim.x * 256) {
    int u = load_idx(ui, e, f3);
    int it = NU + load_idx(ii, e, f4);
    int p1 = atomicAdd(&cur[u >> NODE_SHIFT], 1);   // LDS atomic
    int p2 = atomicAdd(&cur[it >> NODE_SHIFT], 1);  // LDS atomic
    // pair: lo = dst, hi = src
    pairs[p1] = ((unsigned long long)(unsigned)it << 32) | (unsigned)u;
    pairs[p2] = ((unsigned long long)(unsigned)u << 32) | (unsigned)it;
  }
}

// one block per bucket: count degrees of the bucket's node range in LDS,
// then write deg[] with coalesced plain stores (zero-degree nodes get 0).
__global__ __launch_bounds__(256) void k_builddeg(
    const unsigned long long* __restrict__ pairs, const int* __restrict__ bbase,
    int* __restrict__ deg, int N, int NODE_SHIFT, int twoE) {
  __shared__ int ldeg[RNG_MAX];
  const int rng = 1 << NODE_SHIFT;
  for (int j = threadIdx.x; j < rng; j += 256) ldeg[j] = 0;
  __syncthreads();
  const int b = blockIdx.x;
  const int pstart = bbase[b * NBLK];
  const int pend = ((b + 1) * NBLK < NBKT * NBLK) ? bbase[(b + 1) * NBLK] : twoE;
  const int mask = rng - 1;
  for (int i = pstart + (int)threadIdx.x; i < pend; i += 256) {
    int dst = (int)(unsigned)(pairs[i] & 0xffffffffULL);
    atomicAdd(&ldeg[dst & mask], 1);  // LDS atomic
  }
  __syncthreads();
  const int node0 = b << NODE_SHIFT;
  for (int j = threadIdx.x; j < rng; j += 256) {
    int n = node0 + j;
    if (n < N) deg[n] = ldeg[j];
  }
}

// one block per bucket: scatter the bucket's pairs into cols using LDS
// cursors; writes land in the bucket's contiguous cols window (L2-resident).
__global__ __launch_bounds__(256) void k_scatter_n(
    const unsigned long long* __restrict__ pairs, const int* __restrict__ bbase,
    const int* __restrict__ row_ptr, int* __restrict__ cols,
    int NODE_SHIFT, int twoE) {
  __shared__ int lcnt[RNG_MAX];
  const int rng = 1 << NODE_SHIFT;
  for (int j = threadIdx.x; j < rng; j += 256) lcnt[j] = 0;
  __syncthreads();
  const int b = blockIdx.x;
  const int pstart = bbase[b * NBLK];
  const int pend = ((b + 1) * NBLK < NBKT * NBLK) ? bbase[(b + 1) * NBLK] : twoE;
  const int mask = rng - 1;
  for (int i = pstart + (int)threadIdx.x; i < pend; i += 256) {
    unsigned long long p = pairs[i];
    int dst = (int)(unsigned)(p & 0xffffffffULL);
    int src = (int)(unsigned)(p >> 32);
    int slot = row_ptr[dst] + atomicAdd(&lcnt[dst & mask], 1);  // LDS atomic
    cols[slot] = src;
  }
}

// ---------------- legacy single-pass scatter (ws_size fallback; round-4) ------
__global__ __launch_bounds__(256) void k_scatter_legacy(
    const int* __restrict__ ui, const int* __restrict__ ii,
    const int* __restrict__ flags, const int* __restrict__ row_ptr,
    int* __restrict__ cnt, int* __restrict__ cols, int E, int NU, int N) {
  const int f3 = flags[3], f4 = flags[4];
  const int grp = blockIdx.x & 7;
  const int gb = blockIdx.x >> 3;
  const int ngb = gridDim.x >> 3;
  const int chunk = (N + 7) >> 3;
  const int rlo = grp * chunk;
  const int rhi = min(N, rlo + chunk);
  for (int e = gb * 256 + (int)threadIdx.x; e < E; e += ngb * 256) {
    int u = load_idx(ui, e, f3);
    int it = NU + load_idx(ii, e, f4);
    if (u >= rlo && u < rhi)
      cols[row_ptr[u] + atomicAdd(&cnt[u], 1)] = it;
    if (it >= rlo && it < rhi)
      cols[row_ptr[it] + atomicAdd(&cnt[it], 1)] = u;
  }
}

// ---------------- pure gather: agg[r][:] = sum_{c in N(r)} gsrc[c][:] ----------------
// (round-4 structure; plain loads — nt hints regressed in round 5.)
// Wave layout: lane = 8*g + t; group g does 4 edges/iter via one int4 cols
// load; lane t covers dims 8t..8t+7 as one 16B load. dinv_r applied later.
__global__ __launch_bounds__(256) void k_gather(
    const int* __restrict__ row_ptr, const int* __restrict__ deg,
    const int* __restrict__ cols, const f16* __restrict__ gsrc,
    float* __restrict__ agg, int N) {
  const int wave = threadIdx.x >> 6;
  const int lane = threadIdx.x & 63;
  const int g = lane >> 3;  // edge-slot group 0..7
  const int t = lane & 7;   // dim chunk: dims 8t..8t+7
  const int stride = gridDim.x * 4;
  const f16* pb = gsrc + (t << 3);

  for (int r = blockIdx.x * 4 + wave; r < N; r += stride) {
    const int start = row_ptr[r];  // multiple of 4 (padded CSR)
    const int end = start + deg[r];

    float sv[8] = {0.f, 0.f, 0.f, 0.f, 0.f, 0.f, 0.f, 0.f};

    int e = start;
    if (e + 32 <= end) {
      int4 c4 = *(const int4*)(cols + e + (g << 2));  // 16B aligned
      for (; e + 32 <= end;) {
        // prefetch next iteration's cols (stays inside padded allocation;
        // garbage indices are never dereferenced)
        int4 c4n = *(const int4*)(cols + e + 32 + (g << 2));
        half8 v0 = *(const half8*)(pb + ((size_t)c4.x << 6));
        half8 v1 = *(const half8*)(pb + ((size_t)c4.y << 6));
        half8 v2 = *(const half8*)(pb + ((size_t)c4.z << 6));
        half8 v3 = *(const half8*)(pb + ((size_t)c4.w << 6));
#pragma unroll
        for (int k = 0; k < 8; ++k)
          sv[k] += ((float)v0[k] + (float)v1[k]) + ((float)v2[k] + (float)v3[k]);
        e += 32;
        c4 = c4n;
      }
    }
    int rem = end - e;
    if (rem > 0) {
      int4 c4 = *(const int4*)(cols + e + (g << 2));
      int k0 = g << 2;
#pragma unroll
      for (int j = 0; j < 4; ++j) {
        int cj = (j == 0) ? c4.x : (j == 1) ? c4.y : (j == 2) ? c4.z : c4.w;
        if (k0 + j < rem) {
          half8 v = *(const half8*)(pb + ((size_t)cj << 6));
#pragma unroll
          for (int k = 0; k < 8; ++k) sv[k] += (float)v[k];
        }
      }
    }

    // butterfly over the 8 edge groups -> every lane holds the full sums
#pragma unroll
    for (int k = 0; k < 8; ++k) {
      float s = sv[k];
      s += __shfl_xor(s, 8);
      s += __shfl_xor(s, 16);
      s += __shfl_xor(s, 32);
      sv[k] = s;
    }

    // lane (g,t) writes dim t*8+g with value sv[g]  (static-index select chain)
    float v = sv[0];
#pragma unroll
    for (int j = 1; j < 8; ++j) v = (g == j) ? sv[j] : v;
    agg[(size_t)r * DIM + (t << 3) + g] = v;
  }
}

// ---------------- streaming Linear + ReLU (+ final combine) ----------------
// Round-9 rocprof: old shfl-based version = 134 us with HBM 9%, VALU 31%,
// occupancy 29%, 8.1M LDS bank conflicts. Diagnosis:
//  (a) __shfl(a,k) -> ds_bpermute: 64 LDS-pipe ops/row feeding a serial FMA
//      chain, one row in flight -> latency/LDS-pipe-bound.
//  (b) transposed Wt staging writes = 32-way bank conflict (the 8.1M).
// Fix: (1) v_readlane broadcast (constant lane per unrolled k) — zero LDS in
// the hot loop, bit-identical accumulation order; (2) TWO consecutive rows
// in flight per wave (both loads issued together, interleaved chains);
// (3) rotation-swizzled Wt staging (bank = (d+k)&31 -> conflict-free both
// directions).
__device__ __forceinline__ float bcast_lane(float v, int k) {
  return __int_as_float(__builtin_amdgcn_readlane(__float_as_int(v), k));
}

template <int MODE>
__global__ __launch_bounds__(256, 4) void k_linear(
    const float* __restrict__ agg, const int* __restrict__ deg,
    const void* __restrict__ Wbase, int layer, const int* __restrict__ flags,
    const void* __restrict__ xA, const void* __restrict__ xB, int split,
    const f16* __restrict__ h1s, const f16* __restrict__ h2s,
    f16* __restrict__ houts, float* __restrict__ fout, int N) {
  const int fw = flags[2];
  __shared__ float Wt[64 * 64];  // Wt[k*64 + ((d+k)&63)] = W[l][d][k]
  for (int i = threadIdx.x; i < 64 * 64; i += 256) {
    float wv = fw ? ((const float*)Wbase)[layer * 4096 + i]
                  : __bfloat162float(((const __hip_bfloat16*)Wbase)[layer * 4096 + i]);
    int d = i >> 6, k = i & 63;
    Wt[(k << 6) + ((d + k) & 63)] = wv;  // rotation swizzle: conflict-free
  }
  __syncthreads();

  const int wave = threadIdx.x >> 6;
  const int lane = threadIdx.x & 63;  // = output dim d

  float w[64];  // W[d=lane][k], k = 0..63 (static indices only)
#pragma unroll
  for (int k = 0; k < 64; ++k) w[k] = Wt[(k << 6) + ((lane + k) & 63)];

  const int fu = flags[0], fi = flags[1];
  const int stride2 = gridDim.x * 8;  // row-pairs per sweep

  auto epilogue = [&](int r, float lin) {
    const int dr = deg[r];
    const float dinv_r = rsqrtf((float)dr + 1e-10f);
    float hn = lin * dinv_r;
    hn = hn > 0.f ? hn : 0.f;
    size_t o = (size_t)r * DIM + lane;
    if constexpr (MODE == 2) {
      float xr;
      if (r < split) {
        size_t ox = (size_t)r * DIM + lane;
        xr = fu ? ((const float*)xA)[ox]
                : __bfloat162float(((const __hip_bfloat16*)xA)[ox]);
      } else {
        size_t ox = (size_t)(r - split) * DIM + lane;
        xr = fi ? ((const float*)xB)[ox]
                : __bfloat162float(((const __hip_bfloat16*)xB)[ox]);
      }
      float sr = sqrtf((float)dr + 1e-10f);  // un-scale stored h1s/h2s
      float h1v = (float)h1s[o] * sr;
      float h2v = (float)h2s[o] * sr;
      fout[o] = (xr + h1v + h2v + hn) * 0.25f;  // FLOAT32 output
    } else {
      houts[o] = (f16)(hn * dinv_r);
    }
  };

  for (int r = (blockIdx.x * 4 + wave) * 2; r < N; r += stride2) {
    const int r1 = r + 1;
    const bool has1 = (r1 < N);
    float a0 = agg[(size_t)r * DIM + lane];
    float a1 = has1 ? agg[(size_t)r1 * DIM + lane] : 0.f;
    float lin0 = 0.f, lin1 = 0.f;
#pragma unroll
    for (int k = 0; k < 64; ++k) {
      float s0 = bcast_lane(a0, k);
      float s1 = bcast_lane(a1, k);
      lin0 += s0 * w[k];
      lin1 += s1 * w[k];
    }
    epilogue(r, lin0);
    if (has1) epilogue(r1, lin1);
  }
}

extern "C" void kernel_launch(void* const* d_in, const int* in_sizes, int n_in,
                              void* d_out, int out_size, void* d_ws, size_t ws_size,
                              hipStream_t stream) {
  const void* user_e = d_in[0];
  const void* item_e = d_in[1];
  const void* W = d_in[2];
  const int* ui = (const int*)d_in[3];
  const int* ii = (const int*)d_in[4];

  const int NU = in_sizes[0] / DIM;
  const int NI = in_sizes[1] / DIM;
  const int N = NU + NI;
  const int E = in_sizes[3];
  float* out = (float*)d_out;  // OUTPUT IS FLOAT32

  // node-space bucket geometry: rng = 2^NODE_SHIFT nodes per bucket
  int NODE_SHIFT = 0;
  while (((N + (1 << NODE_SHIFT) - 1) >> NODE_SHIFT) > NBKT) NODE_SHIFT++;
  const bool node_ok = ((1 << NODE_SHIFT) <= RNG_MAX);  // N <= NBKT*RNG_MAX
  const long long CE = 2LL * E + 4LL * N + 64;  // padded CSR capacity
  const int NSEG2 = NBKT * NBLK;  // 262144 count-matrix entries
  const int twoE = 2 * E;

  // Workspace (~140 MB for N=150k, E=3M)
  auto align = [](size_t x) { return (x + 255) & ~(size_t)255; };
  char* w = (char*)d_ws;
  size_t off = 0;
  int* deg = (int*)(w + off);      off += align((size_t)N * 4);
  int* cnt = (int*)(w + off);      off += align((size_t)N * 4);
  int* bsum = (int*)(w + off);     off += align((size_t)4096 * 4);
  int* flags = (int*)(w + off);    off += align(256);
  size_t meta_zero_bytes = off;
  int* row_ptr = (int*)(w + off);  off += align((size_t)N * 4);
  float* dinv = (float*)(w + off); off += align((size_t)N * 4);
  int* cols = (int*)(w + off);     off += align((size_t)CE * 4);
  f16* xs = (f16*)(w + off);       off += align((size_t)N * DIM * 2);
  f16* h1s = (f16*)(w + off);      off += align((size_t)N * DIM * 2);
  f16* h2s = (f16*)(w + off);      off += align((size_t)N * DIM * 2);
  int* bcnt = (int*)(w + off);     off += align((size_t)NSEG2 * 4);
  int* bbase = (int*)(w + off);    off += align((size_t)NSEG2 * 4);
  // pairs (CSR build) and agg (layers) overlay: lifetimes don't intersect
  size_t off_union = off;
  float* agg = (float*)(w + off_union);
  unsigned long long* pairs = (unsigned long long*)(w + off_union);
  size_t agg_bytes = (size_t)N * DIM * 4;
  size_t pairs_bytes = (size_t)twoE * 8;
  size_t need_new = off_union + align(pairs_bytes > agg_bytes ? pairs_bytes : agg_bytes);
  const bool use2pass = node_ok && ((ws_size == 0) || (ws_size >= need_new));

  hipMemsetAsync(d_ws, 0, meta_zero_bytes, stream);

  k_detect<<<1, 64, 0, stream>>>((const unsigned short*)user_e,
                                 (const unsigned short*)item_e,
                                 (const unsigned short*)W,
                                 (const unsigned int*)ui,
                                 (const unsigned int*)ii, flags);

  const int TPB = 256;
  int nb = (N + 255) / 256;  // 586 for N=150000, must be <= 1024

  if (use2pass) {
    // ---- node-space binning: no global atomics anywhere ----
    k_bcount_n<<<NBLK, 256, 0, stream>>>(ui, ii, flags, bcnt, E, NU, NODE_SHIFT);
    int nb2 = NSEG2 / 256;  // 1024
    g_scan1<<<nb2, 256, 0, stream>>>(bcnt, bsum, NSEG2);
    k_scan2<<<1, 1024, 0, stream>>>(bsum, nb2);
    g_scan3<<<nb2, 256, 0, stream>>>(bcnt, bsum, bbase, NSEG2);
    k_bin2_n<<<NBLK, 256, 0, stream>>>(ui, ii, flags, bbase, pairs, E, NU,
                                       NODE_SHIFT);
    k_builddeg<<<NBKT, 256, 0, stream>>>(pairs, bbase, deg, N, NODE_SHIFT, twoE);
    k_dinv<<<(N + TPB - 1) / TPB, TPB, 0, stream>>>(deg, dinv, N);
    k_prescale<<<(N * (DIM / 4) + TPB - 1) / TPB, TPB, 0, stream>>>(
        user_e, item_e, NU, dinv, flags, xs, N);
    k_scan1<<<nb, 256, 0, stream>>>(deg, bsum, N);
    k_scan2<<<1, 1024, 0, stream>>>(bsum, nb);
    k_scan3<<<nb, 256, 0, stream>>>(deg, bsum, row_ptr, N);
    k_scatter_n<<<NBKT, 256, 0, stream>>>(pairs, bbase, row_ptr, cols,
                                          NODE_SHIFT, twoE);
  } else {
    // ---- fallback: global-atomic degree + legacy chunked scatter ----
    k_degree_legacy<<<2048, TPB, 0, stream>>>(ui, ii, flags, deg, E, NU, N);
    k_dinv<<<(N + TPB - 1) / TPB, TPB, 0, stream>>>(deg, dinv, N);
    k_prescale<<<(N * (DIM / 4) + TPB - 1) / TPB, TPB, 0, stream>>>(
        user_e, item_e, NU, dinv, flags, xs, N);
    k_scan1<<<nb, 256, 0, stream>>>(deg, bsum, N);
    k_scan2<<<1, 1024, 0, stream>>>(bsum, nb);
    k_scan3<<<nb, 256, 0, stream>>>(deg, bsum, row_ptr, N);
    k_scatter_legacy<<<2048, 256, 0, stream>>>(ui, ii, flags, row_ptr, cnt,
                                               cols, E, NU, N);
  }

  const int GGRID = 4096;  // gather: fine-grained for load balance + full residency
  const int LGRID = 2048;

  k_gather<<<GGRID, 256, 0, stream>>>(row_ptr, deg, cols, xs, agg, N);
  k_linear<0><<<LGRID, 256, 0, stream>>>(agg, deg, W, 0, flags, user_e, item_e, NU,
                                         nullptr, nullptr, h1s, nullptr, N);
  k_gather<<<GGRID, 256, 0, stream>>>(row_ptr, deg, cols, h1s, agg, N);
  k_linear<1><<<LGRID, 256, 0, stream>>>(agg, deg, W, 1, flags, user_e, item_e, NU,
                                         nullptr, nullptr, h2s, nullptr, N);
  k_gather<<<GGRID, 256, 0, stream>>>(row_ptr, deg, cols, h2s, agg, N);
  k_linear<2><<<LGRID, 256, 0, stream>>>(agg, deg, W, 2, flags, user_e, item_e, NU,
                                         h1s, h2s, nullptr, out, N);
}